// Round 4
// baseline (84.602 us; speedup 1.0000x reference)
//
#include <hip/hip_runtime.h>

// Chamfer distance, fp32 in/out, A,B = [4][8192][3], via bf16-split MFMA.
// d^2(a,b) = a^2 + b^2 - 2ab as a K=15 inner product of bf16 embedding vectors:
//  k0-2 : (a2h,a2l,a2ll) x 1        (3-way RTNE bf16 split of |a|^2)
//  k3-5 : 1 x (b2h,b2l,b2ll)
//  k6-8 : (-2a)_h x b_h   per coord
//  k9-11: (-2a)_h x b_l
//  k12-14: (-2a)_l x b_h
//  k15  : 0
// One v_mfma_f32_32x32x16_bf16 = 1024 pair d^2 values; min3-merge into fp32 acc.

typedef __bf16 bf16x8 __attribute__((ext_vector_type(8)));
typedef float f32x16 __attribute__((ext_vector_type(16)));
typedef unsigned short u16;

constexpr int NB = 4;
constexpr int NPTS = 8192;
constexpr int NROWS = 2 * NB * NPTS;   // 65536
constexpr int COLSPLIT = 16;           // 512 cols per block
constexpr int CT = 16;                 // col tiles (32 cols each) per block
constexpr int ROWS_PER_BLK = 512;      // 4 waves x 4 frags x 32 rows
constexpr int ROWBLKS = NPTS / ROWS_PER_BLK; // 16
// grid = 2*NB*ROWBLKS*COLSPLIT = 2048

// ws layout: rowT 2MB @0 | colT 2MB @2MB | part [16][65536] f32 4MB @4MB
constexpr size_t ROWT_OFF = 0;
constexpr size_t COLT_OFF = 2u << 20;
constexpr size_t PART_OFF = 4u << 20;

__device__ __forceinline__ float bsplit(float x, u16& hbits, float& hf) {
    unsigned u = __float_as_uint(x);
    unsigned r = (u + 0x7FFFu + ((u >> 16) & 1u)) & 0xFFFF0000u;  // RTNE bf16
    hbits = (u16)(r >> 16);
    hf = __uint_as_float(r);
    return x - hf;   // exact
}

__global__ __launch_bounds__(256)
void chamfer_prep_kernel(const float* __restrict__ A, const float* __restrict__ B,
                         u16* __restrict__ rowT, u16* __restrict__ colT) {
    int idx = blockIdx.x * 256 + threadIdx.x;       // 0..65535
    int pt = idx & (NPTS - 1);
    int batch = (idx >> 13) & (NB - 1);
    int set = idx >> 15;                             // 0=A, 1=B
    const float* src = (set ? B : A) + ((size_t)batch * NPTS + pt) * 3;
    float x = src[0], y = src[1], z = src[2];
    float s2 = fmaf(x, x, fmaf(y, y, z * z));
    float hf, h2;
    u16 s2h, s2l, s2ll, xh, xl, yh, yl, zh, zl, mxh, mxl, myh, myl, mzh, mzl, dummy;
    float r1 = bsplit(s2, s2h, hf);
    float r2 = bsplit(r1, s2l, h2);
    bsplit(r2, s2ll, h2);
    float t;
    t = bsplit(x, xh, hf);        bsplit(t, xl, h2);
    t = bsplit(y, yh, hf);        bsplit(t, yl, h2);
    t = bsplit(z, zh, hf);        bsplit(t, zl, h2);
    t = bsplit(-2.0f * x, mxh, hf); bsplit(t, mxl, h2);
    t = bsplit(-2.0f * y, myh, hf); bsplit(t, myl, h2);
    t = bsplit(-2.0f * z, mzh, hf); bsplit(t, mzl, h2);
    (void)dummy;
    const unsigned ONE = 0x3F80u;
    #define PK(a, b) ((unsigned)(a) | ((unsigned)(b) << 16))
    // row role: s2h s2l s2ll 1 1 1 | mxh myh mzh | mxh myh mzh | mxl myl mzl | 0
    uint4 rw0 = make_uint4(PK(s2h, s2l), PK(s2ll, ONE), PK(ONE, ONE), PK(mxh, myh));
    uint4 rw1 = make_uint4(PK(mzh, mxh), PK(myh, mzh), PK(mxl, myl), PK(mzl, 0));
    // col role: 1 1 1 s2h s2l s2ll | xh yh zh | xl yl zl | xh yh zh | 0
    uint4 cw0 = make_uint4(PK(ONE, ONE), PK(ONE, s2h), PK(s2l, s2ll), PK(xh, yh));
    uint4 cw1 = make_uint4(PK(zh, xl), PK(yl, zl), PK(xh, yh), PK(zh, 0));
    #undef PK
    uint4* rp = (uint4*)(rowT + (size_t)idx * 16);
    uint4* cp = (uint4*)(colT + (size_t)idx * 16);
    rp[0] = rw0; rp[1] = rw1;
    cp[0] = cw0; cp[1] = cw1;
}

__global__ __launch_bounds__(256, 3)
void chamfer_minmfma_kernel(const u16* __restrict__ rowT,
                            const u16* __restrict__ colT,
                            float* __restrict__ part) {
    int bid = blockIdx.x;
    int colsp  = bid & (COLSPLIT - 1); bid >>= 4;
    int rowblk = bid & (ROWBLKS - 1);  bid >>= 4;
    int batch  = bid & (NB - 1);       bid >>= 2;
    int dir    = bid;                  // 0: rows=A cols=B, 1: rows=B cols=A
    const u16* rptr = rowT + (((size_t)(dir * NB + batch) * NPTS) + rowblk * ROWS_PER_BLK) * 16;
    const u16* cptr = colT + (((size_t)((dir ^ 1) * NB + batch) * NPTS) + colsp * 512) * 16;

    int lane = threadIdx.x & 63;
    int wave = threadIdx.x >> 6;
    int l31 = lane & 31, lh = lane >> 5;

    __shared__ uint4 stage[CT * 64];       // 16 KB, frag-ordered B tiles
    __shared__ float red[32 * 260 + 4];    // ~33 KB transpose table

    // A fragments: 4 x 32 rows per wave; lane row = l31, k-half = lh.
    bf16x8 af[4];
    #pragma unroll
    for (int f = 0; f < 4; ++f)
        af[f] = *(const bf16x8*)(rptr + (wave * 128 + f * 32 + l31) * 16 + lh * 8);

    f32x16 acc[4];
    #pragma unroll
    for (int f = 0; f < 4; ++f)
        #pragma unroll
        for (int j = 0; j < 16; ++j) acc[f][j] = 3.0e38f;
    f32x16 zf;
    #pragma unroll
    for (int j = 0; j < 16; ++j) zf[j] = 0.0f;

    // Stage B tiles: LDS frag order u4[c*64 + h*32 + p]; swizzle on the global side
    // so LDS writes are linear/conflict-free.
    #pragma unroll
    for (int j = 0; j < 4; ++j) {
        int d = j * 256 + threadIdx.x;
        int c = d >> 6, rem = d & 63;
        int h = rem >> 5, p = rem & 31;
        stage[d] = ((const uint4*)cptr)[(c * 32 + p) * 2 + h];
    }
    __syncthreads();

    const bf16x8* bt = (const bf16x8*)stage;
    #pragma unroll
    for (int cp = 0; cp < CT / 2; ++cp) {
        bf16x8 b0 = bt[(2 * cp) * 64 + lh * 32 + l31];
        bf16x8 b1 = bt[(2 * cp + 1) * 64 + lh * 32 + l31];
        #pragma unroll
        for (int f = 0; f < 4; ++f) {
            f32x16 d0 = __builtin_amdgcn_mfma_f32_32x32x16_bf16(af[f], b0, zf, 0, 0, 0);
            f32x16 d1 = __builtin_amdgcn_mfma_f32_32x32x16_bf16(af[f], b1, zf, 0, 0, 0);
            #pragma unroll
            for (int j = 0; j < 16; ++j)
                acc[f][j] = fminf(acc[f][j], fminf(d0[j], d1[j]));   // v_min3
        }
    }

    // Epilogue: two phases of 256 rows through the LDS transpose table.
    // D layout: value (lane, reg j) = S[row = (j&3)+8*(j>>2)+4*lh, col = l31].
    int growbase = (dir * NB + batch) * NPTS + rowblk * ROWS_PER_BLK;
    float* po = part + (size_t)colsp * NROWS + growbase;
    #pragma unroll
    for (int ph = 0; ph < 2; ++ph) {
        __syncthreads();
        if ((wave >> 1) == ph) {
            int wbase = (wave & 1) * 128;
            #pragma unroll
            for (int f = 0; f < 4; ++f) {
                #pragma unroll
                for (int g = 0; g < 4; ++g) {
                    int r = wbase + f * 32 + 8 * g + 4 * lh;
                    *(float4*)&red[l31 * 260 + r] =
                        make_float4(acc[f][4*g], acc[f][4*g+1], acc[f][4*g+2], acc[f][4*g+3]);
                }
            }
        }
        __syncthreads();
        int t = threadIdx.x;
        float m = 3.0e38f;
        #pragma unroll
        for (int k = 0; k < 32; ++k) m = fminf(m, red[k * 260 + t]);
        po[ph * 256 + t] = m;
    }
}

__global__ __launch_bounds__(256)
void chamfer_reduce_kernel(const float* __restrict__ part, float* __restrict__ out) {
    constexpr float SCALE = 1.0f / (NB * NPTS * 12.8f);
    int r0 = (blockIdx.x * 256 + threadIdx.x) * 4;
    float4 m = *(const float4*)(part + r0);
    #pragma unroll
    for (int s = 1; s < COLSPLIT; ++s) {
        float4 v = *(const float4*)(part + (size_t)s * NROWS + r0);
        m.x = fminf(m.x, v.x); m.y = fminf(m.y, v.y);
        m.z = fminf(m.z, v.z); m.w = fminf(m.w, v.w);
    }
    float s = sqrtf(fmaxf(m.x, 0.f)) + sqrtf(fmaxf(m.y, 0.f))
            + sqrtf(fmaxf(m.z, 0.f)) + sqrtf(fmaxf(m.w, 0.f));
    #pragma unroll
    for (int off = 32; off >= 1; off >>= 1) s += __shfl_down(s, off, 64);
    __shared__ float redl[4];
    if ((threadIdx.x & 63) == 0) redl[threadIdx.x >> 6] = s;
    __syncthreads();
    if (threadIdx.x == 0)
        atomicAdd(out, (redl[0] + redl[1] + redl[2] + redl[3]) * SCALE);
}

extern "C" void kernel_launch(void* const* d_in, const int* in_sizes, int n_in,
                              void* d_out, int out_size, void* d_ws, size_t ws_size,
                              hipStream_t stream) {
    const float* A = (const float*)d_in[0];
    const float* B = (const float*)d_in[1];
    float* out = (float*)d_out;
    u16* rowT = (u16*)((char*)d_ws + ROWT_OFF);
    u16* colT = (u16*)((char*)d_ws + COLT_OFF);
    float* part = (float*)((char*)d_ws + PART_OFF);

    hipMemsetAsync(d_out, 0, sizeof(float), stream);
    chamfer_prep_kernel<<<NROWS / 256, 256, 0, stream>>>(A, B, rowT, colT);
    chamfer_minmfma_kernel<<<2 * NB * ROWBLKS * COLSPLIT, 256, 0, stream>>>(rowT, colT, part);
    chamfer_reduce_kernel<<<NROWS / 4 / 256, 256, 0, stream>>>(part, out);
}

// Round 5
// 51.168 us; speedup vs baseline: 1.6534x; 1.6534x over previous
//
#include <hip/hip_runtime.h>

// Chamfer distance, fp32 in/out, A,B = [4][8192][3], via bf16-split MFMA.
// Embedding (validated R4, absmax 0.0): d^2(a,b) = K=15 bf16 inner product:
//  k0-2:(a2h,a2l,a2ll)x1 | k3-5:1x(b2h,b2l,b2ll) | k6-8:(-2a)_h x b_h
//  k9-11:(-2a)_h x b_l | k12-14:(-2a)_l x b_h | k15:0
// One v_mfma_f32_32x32x16_bf16 = 1024 pair d^2 values; min3-merge into fp32.
// Block = 64 rows x ALL 8192 cols (4 waves split cols 4-way) -> row-min
// completes in-block: no atomics, no init, tiny writes.

typedef __bf16 bf16x8 __attribute__((ext_vector_type(8)));
typedef float f32x16 __attribute__((ext_vector_type(16)));
typedef unsigned short u16;

constexpr int NB = 4;
constexpr int NPTS = 8192;
constexpr int NROWS = 2 * NB * NPTS;     // 65536
constexpr int ROWS_PER_BLK = 64;         // 2 frags
constexpr int ROWBLKS = NPTS / ROWS_PER_BLK;  // 128
constexpr int CHUNK_TILES = 16;          // 512 cols per chunk, 16 KB
constexpr int NCHUNK = NPTS / (32 * CHUNK_TILES);  // 16

// ws: rowT 2MB @0 | colT 2MB @2MB | ws_min 256KB @4MB
constexpr size_t COLT_OFF = 2u << 20;
constexpr size_t WSMIN_OFF = 4u << 20;

__device__ __forceinline__ float bsplit(float x, u16& hbits, float& hf) {
    unsigned u = __float_as_uint(x);
    unsigned r = (u + 0x7FFFu + ((u >> 16) & 1u)) & 0xFFFF0000u;  // RTNE bf16
    hbits = (u16)(r >> 16);
    hf = __uint_as_float(r);
    return x - hf;   // exact
}

__device__ __forceinline__ void gload_lds16(const uint4* g, uint4* l) {
    __builtin_amdgcn_global_load_lds(
        (const __attribute__((address_space(1))) void*)g,
        (__attribute__((address_space(3))) void*)l, 16, 0, 0);
}

__global__ __launch_bounds__(256)
void chamfer_prep_kernel(const float* __restrict__ A, const float* __restrict__ B,
                         u16* __restrict__ rowT, u16* __restrict__ colT) {
    int idx = blockIdx.x * 256 + threadIdx.x;       // 0..65535
    int pt = idx & (NPTS - 1);
    int batch = (idx >> 13) & (NB - 1);
    int set = idx >> 15;                             // 0=A, 1=B
    const float* src = (set ? B : A) + ((size_t)batch * NPTS + pt) * 3;
    float x = src[0], y = src[1], z = src[2];
    float s2 = fmaf(x, x, fmaf(y, y, z * z));
    float hf, h2;
    u16 s2h, s2l, s2ll, xh, xl, yh, yl, zh, zl, mxh, mxl, myh, myl, mzh, mzl;
    float r1 = bsplit(s2, s2h, hf);
    float r2 = bsplit(r1, s2l, h2);
    bsplit(r2, s2ll, h2);
    float t;
    t = bsplit(x, xh, hf);          bsplit(t, xl, h2);
    t = bsplit(y, yh, hf);          bsplit(t, yl, h2);
    t = bsplit(z, zh, hf);          bsplit(t, zl, h2);
    t = bsplit(-2.0f * x, mxh, hf); bsplit(t, mxl, h2);
    t = bsplit(-2.0f * y, myh, hf); bsplit(t, myl, h2);
    t = bsplit(-2.0f * z, mzh, hf); bsplit(t, mzl, h2);
    const unsigned ONE = 0x3F80u;
    #define PK(a, b) ((unsigned)(a) | ((unsigned)(b) << 16))
    uint4 rw0 = make_uint4(PK(s2h, s2l), PK(s2ll, ONE), PK(ONE, ONE), PK(mxh, myh));
    uint4 rw1 = make_uint4(PK(mzh, mxh), PK(myh, mzh), PK(mxl, myl), PK(mzl, 0));
    uint4 cw0 = make_uint4(PK(ONE, ONE), PK(ONE, s2h), PK(s2l, s2ll), PK(xh, yh));
    uint4 cw1 = make_uint4(PK(zh, xl), PK(yl, zl), PK(xh, yh), PK(zh, 0));
    #undef PK
    uint4* rp = (uint4*)(rowT + (size_t)idx * 16);
    uint4* cp = (uint4*)(colT + (size_t)idx * 16);
    rp[0] = rw0; rp[1] = rw1;
    cp[0] = cw0; cp[1] = cw1;
}

__global__ __launch_bounds__(256, 3)
void chamfer_minmfma_kernel(const u16* __restrict__ rowT,
                            const u16* __restrict__ colT,
                            float* __restrict__ ws_min) {
    int bid = blockIdx.x;
    int rowblk = bid & (ROWBLKS - 1); bid >>= 7;
    int batch  = bid & (NB - 1);      bid >>= 2;
    int dir    = bid;
    const u16* rptr = rowT + (((size_t)(dir * NB + batch) * NPTS) + rowblk * 64) * 16;
    const uint4* cptr = (const uint4*)colT + (size_t)((dir ^ 1) * NB + batch) * NPTS * 2;
    float* wout = ws_min + (size_t)(dir * NB + batch) * NPTS + rowblk * 64;

    int lane = threadIdx.x & 63;
    int wave = threadIdx.x >> 6;
    int l31 = lane & 31, lh = lane >> 5;

    // LDS: stage 2x16KB dbuf (main) / tab 4x2176 f + red2 4x68 f (epilogue)
    __shared__ __align__(16) char smraw[35904];
    uint4* stg  = (uint4*)smraw;                    // [2][1024]
    float* tab  = (float*)smraw;                    // [wave*2+frag][34*32]
    float* red2 = (float*)(smraw + 34816);          // [4][68]

    bf16x8 af0 = *(const bf16x8*)(rptr + (0 * 32 + l31) * 16 + lh * 8);
    bf16x8 af1 = *(const bf16x8*)(rptr + (1 * 32 + l31) * 16 + lh * 8);

    f32x16 acc0, acc1, zf;
    #pragma unroll
    for (int j = 0; j < 16; ++j) { acc0[j] = 3.0e38f; acc1[j] = 3.0e38f; zf[j] = 0.0f; }

    // Stage one 16-tile chunk (512 cols) into buffer sel. LDS dest is
    // wave-uniform base + lane*16; global src pre-swizzled to frag order.
    auto stage = [&](int c, int sel) {
        #pragma unroll
        for (int i = 0; i < 4; ++i) {
            int d = wave * 256 + i * 64 + lane;
            int ctl = d >> 6, rem = d & 63;
            int h = rem >> 5, p = rem & 31;
            const uint4* src = cptr + ((size_t)(c * CHUNK_TILES + ctl) * 32 + p) * 2 + h;
            gload_lds16(src, stg + sel * 1024 + wave * 256 + i * 64);
        }
    };

    stage(0, 0);
    for (int c = 0; c < NCHUNK; ++c) {
        __syncthreads();                      // chunk c staged; buf (c+1)&1 free
        if (c + 1 < NCHUNK) stage(c + 1, (c + 1) & 1);
        const uint4* bufc = stg + (c & 1) * 1024;
        #pragma unroll
        for (int tt = 0; tt < 4; tt += 2) {   // wave's 4 tiles of this chunk
            bf16x8 b0 = *(const bf16x8*)&bufc[(wave * 4 + tt) * 64 + lane];
            bf16x8 b1 = *(const bf16x8*)&bufc[(wave * 4 + tt + 1) * 64 + lane];
            f32x16 d0 = __builtin_amdgcn_mfma_f32_32x32x16_bf16(af0, b0, zf, 0, 0, 0);
            f32x16 d1 = __builtin_amdgcn_mfma_f32_32x32x16_bf16(af0, b1, zf, 0, 0, 0);
            #pragma unroll
            for (int j = 0; j < 16; ++j) acc0[j] = fminf(acc0[j], fminf(d0[j], d1[j]));
            d0 = __builtin_amdgcn_mfma_f32_32x32x16_bf16(af1, b0, zf, 0, 0, 0);
            d1 = __builtin_amdgcn_mfma_f32_32x32x16_bf16(af1, b1, zf, 0, 0, 0);
            #pragma unroll
            for (int j = 0; j < 16; ++j) acc1[j] = fminf(acc1[j], fminf(d0[j], d1[j]));
        }
    }
    __syncthreads();   // all waves done with stage LDS; reuse as tables

    // Col-reduce via per-wave LDS table. D layout: (lane,j) -> row=(j&3)+8*(j>>2)+4*lh,
    // col=l31. Write [col][row] stride 34 (2-way bank alias only).
    #pragma unroll
    for (int g = 0; g < 4; ++g) {
        int r0 = 8 * g + 4 * lh;
        float* b0p = tab + (wave * 2 + 0) * 1088 + l31 * 34 + r0;
        float* b1p = tab + (wave * 2 + 1) * 1088 + l31 * 34 + r0;
        b0p[0] = acc0[4*g]; b0p[1] = acc0[4*g+1]; b0p[2] = acc0[4*g+2]; b0p[3] = acc0[4*g+3];
        b1p[0] = acc1[4*g]; b1p[1] = acc1[4*g+1]; b1p[2] = acc1[4*g+2]; b1p[3] = acc1[4*g+3];
    }
    int fr = lane >> 5, r = lane & 31;       // lane L <-> block-row L
    const float* tb = tab + (wave * 2 + fr) * 1088 + r;
    float v = 3.0e38f;
    #pragma unroll
    for (int cc = 0; cc < 32; ++cc) v = fminf(v, tb[cc * 34]);
    red2[wave * 68 + lane] = v;
    __syncthreads();
    if (wave == 0) {
        float m = fminf(fminf(red2[0 * 68 + lane], red2[1 * 68 + lane]),
                        fminf(red2[2 * 68 + lane], red2[3 * 68 + lane]));
        wout[lane] = fmaxf(m, 0.0f);
    }
}

__global__ __launch_bounds__(256)
void chamfer_reduce_kernel(const float* __restrict__ ws_min, float* __restrict__ out) {
    constexpr float SCALE = 1.0f / (NB * NPTS * 12.8f);
    int idx = (blockIdx.x * 256 + threadIdx.x) * 4;
    float4 v = *(const float4*)(ws_min + idx);
    float s = sqrtf(v.x) + sqrtf(v.y) + sqrtf(v.z) + sqrtf(v.w);
    #pragma unroll
    for (int off = 32; off >= 1; off >>= 1) s += __shfl_down(s, off, 64);
    __shared__ float redl[4];
    if ((threadIdx.x & 63) == 0) redl[threadIdx.x >> 6] = s;
    __syncthreads();
    if (threadIdx.x == 0)
        atomicAdd(out, (redl[0] + redl[1] + redl[2] + redl[3]) * SCALE);
}

extern "C" void kernel_launch(void* const* d_in, const int* in_sizes, int n_in,
                              void* d_out, int out_size, void* d_ws, size_t ws_size,
                              hipStream_t stream) {
    const float* A = (const float*)d_in[0];
    const float* B = (const float*)d_in[1];
    float* out = (float*)d_out;
    u16* rowT = (u16*)d_ws;
    u16* colT = (u16*)((char*)d_ws + COLT_OFF);
    float* wsm = (float*)((char*)d_ws + WSMIN_OFF);

    hipMemsetAsync(d_out, 0, sizeof(float), stream);
    chamfer_prep_kernel<<<NROWS / 256, 256, 0, stream>>>(A, B, rowT, colT);
    chamfer_minmfma_kernel<<<2 * NB * ROWBLKS, 256, 0, stream>>>(rowT, colT, wsm);
    chamfer_reduce_kernel<<<NROWS / 4 / 256, 256, 0, stream>>>(wsm, out);
}

// Round 6
// 45.236 us; speedup vs baseline: 1.8702x; 1.1311x over previous
//
#include <hip/hip_runtime.h>

// Chamfer distance, fp32 in/out, A,B = [4][8192][3], via bf16-split MFMA.
// Embedding (HW-validated R4/R5, absmax 0.0): d^2(u,v) = rw(u).cw(v), K=15:
//  rw: s2h s2l s2ll 1 1 1 | mxh myh mzh | mxh myh mzh | mxl myl mzl | 0
//  cw: 1 1 1 s2h s2l s2ll |  xh  yh  zh |  xl  yl  zl |  xh  yh  zh | 0
// SWAPPED operands: stream rw-points as MFMA-A (output rows = min axis),
// resident cw-points as MFMA-B (output cols). Min axis is lane-local in D:
// 16->1 min3 tree per MFMA into a SCALAR acc per frag. No LDS staging, no
// barriers in the main loop, loads go global->VGPR with a depth-4 ring.

typedef __bf16 bf16x8 __attribute__((ext_vector_type(8)));
typedef float f32x16 __attribute__((ext_vector_type(16)));
typedef unsigned short u16;

constexpr int NB = 4;
constexpr int NPTS = 8192;
constexpr int NROWS = 2 * NB * NPTS;           // 65536
constexpr int FRAGS = 4;                        // resident frags -> 128 rows/block
constexpr int ROWS_PER_BLK = FRAGS * 32;        // 128
constexpr int ROWBLKS = NPTS / ROWS_PER_BLK;    // 64
constexpr int TILES = NPTS / 32;                // 256 stream tiles
constexpr int TILES_PER_WAVE = TILES / 4;       // 64
constexpr int DEPTH = 4;                        // prefetch ring

// ws: streamT(rw) 2MB @0 | resT(cw) 2MB @2MB | wout 256KB @4MB
constexpr size_t REST_OFF = 2u << 20;
constexpr size_t WOUT_OFF = 4u << 20;

__device__ __forceinline__ float bsplit(float x, u16& hbits, float& hf) {
    unsigned u = __float_as_uint(x);
    unsigned r = (u + 0x7FFFu + ((u >> 16) & 1u)) & 0xFFFF0000u;  // RTNE bf16
    hbits = (u16)(r >> 16);
    hf = __uint_as_float(r);
    return x - hf;   // exact
}

__global__ __launch_bounds__(256)
void chamfer_prep_kernel(const float* __restrict__ A, const float* __restrict__ B,
                         u16* __restrict__ streamT, u16* __restrict__ resT) {
    int idx = blockIdx.x * 256 + threadIdx.x;       // 0..65535
    int pt = idx & (NPTS - 1);
    int batch = (idx >> 13) & (NB - 1);
    int set = idx >> 15;                             // 0=A, 1=B
    const float* src = (set ? B : A) + ((size_t)batch * NPTS + pt) * 3;
    float x = src[0], y = src[1], z = src[2];
    float s2 = fmaf(x, x, fmaf(y, y, z * z));
    float hf, h2;
    u16 s2h, s2l, s2ll, xh, xl, yh, yl, zh, zl, mxh, mxl, myh, myl, mzh, mzl;
    float r1 = bsplit(s2, s2h, hf);
    float r2 = bsplit(r1, s2l, h2);
    bsplit(r2, s2ll, h2);
    float t;
    t = bsplit(x, xh, hf);          bsplit(t, xl, h2);
    t = bsplit(y, yh, hf);          bsplit(t, yl, h2);
    t = bsplit(z, zh, hf);          bsplit(t, zl, h2);
    t = bsplit(-2.0f * x, mxh, hf); bsplit(t, mxl, h2);
    t = bsplit(-2.0f * y, myh, hf); bsplit(t, myl, h2);
    t = bsplit(-2.0f * z, mzh, hf); bsplit(t, mzl, h2);
    const unsigned ONE = 0x3F80u;
    #define PK(a, b) ((unsigned)(a) | ((unsigned)(b) << 16))
    uint4 rw0 = make_uint4(PK(s2h, s2l), PK(s2ll, ONE), PK(ONE, ONE), PK(mxh, myh));
    uint4 rw1 = make_uint4(PK(mzh, mxh), PK(myh, mzh), PK(mxl, myl), PK(mzl, 0));
    uint4 cw0 = make_uint4(PK(ONE, ONE), PK(ONE, s2h), PK(s2l, s2ll), PK(xh, yh));
    uint4 cw1 = make_uint4(PK(zh, xl), PK(yl, zl), PK(xh, yh), PK(zh, 0));
    #undef PK
    uint4* sp = (uint4*)(streamT + (size_t)idx * 16);
    uint4* rp = (uint4*)(resT + (size_t)idx * 16);
    sp[0] = rw0; sp[1] = rw1;
    rp[0] = cw0; rp[1] = cw1;
}

__device__ __forceinline__ float tree16(const f32x16& d) {
    float m0 = fminf(fminf(d[0],  d[1]),  d[2]);    // -> v_min3
    float m1 = fminf(fminf(d[3],  d[4]),  d[5]);
    float m2 = fminf(fminf(d[6],  d[7]),  d[8]);
    float m3 = fminf(fminf(d[9],  d[10]), d[11]);
    float m4 = fminf(fminf(d[12], d[13]), d[14]);
    float n0 = fminf(fminf(m0, m1), m2);
    float n1 = fminf(fminf(m3, m4), d[15]);
    return fminf(n0, n1);
}

__global__ __launch_bounds__(256)
void chamfer_minmfma_kernel(const u16* __restrict__ streamT,
                            const u16* __restrict__ resT,
                            float* __restrict__ wout) {
    int bid = blockIdx.x;
    int rowblk = bid & (ROWBLKS - 1); bid >>= 6;
    int batch  = bid & (NB - 1);      bid >>= 2;
    int dir    = bid;

    int lane = threadIdx.x & 63;
    int wave = threadIdx.x >> 6;
    int l31 = lane & 31, lh = lane >> 5;

    // Resident B-operand: this block's 128 output points (cw vectors).
    const u16* rbase = resT + (((size_t)(dir * NB + batch) * NPTS) + rowblk * ROWS_PER_BLK) * 16;
    bf16x8 res[FRAGS];
    #pragma unroll
    for (int f = 0; f < FRAGS; ++f)
        res[f] = *(const bf16x8*)(rbase + (f * 32 + l31) * 16 + lh * 8);

    // Stream A-operand: the other set's points, wave-partitioned tiles.
    const uint4* wp = (const uint4*)streamT
                    + (size_t)((dir ^ 1) * NB + batch) * NPTS * 2
                    + (size_t)wave * TILES_PER_WAVE * 64
                    + (l31 * 2 + lh);

    f32x16 zf;
    #pragma unroll
    for (int j = 0; j < 16; ++j) zf[j] = 0.0f;

    float accf[FRAGS];
    #pragma unroll
    for (int f = 0; f < FRAGS; ++f) accf[f] = 3.0e38f;

    uint4 pipe[DEPTH];
    #pragma unroll
    for (int i = 0; i < DEPTH; ++i) pipe[i] = wp[i * 64];

    for (int t = 0; t < TILES_PER_WAVE; t += DEPTH) {
        #pragma unroll
        for (int u = 0; u < DEPTH; ++u) {
            uint4 cur = pipe[u];
            // Tail prefetch overreads into resT region: valid memory, never used.
            pipe[u] = wp[(t + u + DEPTH) * 64];
            bf16x8 aop = __builtin_bit_cast(bf16x8, cur);
            #pragma unroll
            for (int f = 0; f < FRAGS; ++f) {
                f32x16 d = __builtin_amdgcn_mfma_f32_32x32x16_bf16(aop, res[f], zf, 0, 0, 0);
                accf[f] = fminf(accf[f], tree16(d));
            }
        }
    }

    // Fold the lh-halves (lane and lane^32 cover complementary stream rows).
    #pragma unroll
    for (int f = 0; f < FRAGS; ++f)
        accf[f] = fminf(accf[f], __shfl_xor(accf[f], 32, 64));

    // Cross-wave merge (each wave covered a quarter of the stream tiles).
    __shared__ float part[4][ROWS_PER_BLK];
    if (lh == 0) {
        #pragma unroll
        for (int f = 0; f < FRAGS; ++f) part[wave][f * 32 + l31] = accf[f];
    }
    __syncthreads();
    int tid = threadIdx.x;
    if (tid < ROWS_PER_BLK) {
        float m = fminf(fminf(part[0][tid], part[1][tid]),
                        fminf(part[2][tid], part[3][tid]));
        wout[(size_t)(dir * NB + batch) * NPTS + rowblk * ROWS_PER_BLK + tid] = fmaxf(m, 0.0f);
    }
}

__global__ __launch_bounds__(1024)
void chamfer_reduce_kernel(const float* __restrict__ wout, float* __restrict__ out) {
    constexpr float SCALE = 1.0f / (NB * NPTS * 12.8f);
    const float4* p = (const float4*)wout;           // 16384 float4
    float s = 0.0f;
    #pragma unroll
    for (int k = 0; k < 16; ++k) {
        float4 v = p[threadIdx.x + k * 1024];
        s += sqrtf(v.x) + sqrtf(v.y) + sqrtf(v.z) + sqrtf(v.w);
    }
    #pragma unroll
    for (int off = 32; off >= 1; off >>= 1) s += __shfl_down(s, off, 64);
    __shared__ float red[16];
    if ((threadIdx.x & 63) == 0) red[threadIdx.x >> 6] = s;
    __syncthreads();
    if (threadIdx.x == 0) {
        float tot = 0.0f;
        #pragma unroll
        for (int w = 0; w < 16; ++w) tot += red[w];
        out[0] = tot * SCALE;
    }
}

extern "C" void kernel_launch(void* const* d_in, const int* in_sizes, int n_in,
                              void* d_out, int out_size, void* d_ws, size_t ws_size,
                              hipStream_t stream) {
    const float* A = (const float*)d_in[0];
    const float* B = (const float*)d_in[1];
    float* out = (float*)d_out;
    u16* streamT = (u16*)d_ws;
    u16* resT = (u16*)((char*)d_ws + REST_OFF);
    float* wo = (float*)((char*)d_ws + WOUT_OFF);

    chamfer_prep_kernel<<<NROWS / 256, 256, 0, stream>>>(A, B, streamT, resT);
    chamfer_minmfma_kernel<<<2 * NB * ROWBLKS, 256, 0, stream>>>(streamT, resT, wo);
    chamfer_reduce_kernel<<<1, 1024, 0, stream>>>(wo, out);
}